// Round 14
// baseline (62.100 us; speedup 1.0000x reference)
//
#include <hip/hip_runtime.h>

#define N 4096
#define NBIN 1024
#define LOG2E 1.4426950408889634f

__device__ __forceinline__ float fast_exp2(float x) {
#if __has_builtin(__builtin_amdgcn_exp2f)
    return __builtin_amdgcn_exp2f(x);
#else
    return exp2f(x);
#endif
}

__device__ float block_reduce_sum(float v) {
    __shared__ float red[16];
    int lane = threadIdx.x & 63;
    int wid = threadIdx.x >> 6;
    #pragma unroll
    for (int off = 32; off; off >>= 1) v += __shfl_down(v, off, 64);
    if (lane == 0) red[wid] = v;
    __syncthreads();
    if (threadIdx.x == 0) {
        int nw = (int)(blockDim.x >> 6);
        float s = red[0];
        for (int w = 1; w < nw; ++w) s += red[w];
        red[0] = s;
    }
    __syncthreads();
    float r = red[0];
    __syncthreads();
    return r;
}

// Combined (sum, sumsq, min, max) single-pass block reduction, 1024 threads.
__device__ float4 block_reduce_stats(float s, float sq, float mn, float mx) {
    __shared__ float4 red4[16];
    int lane = threadIdx.x & 63;
    int wid = threadIdx.x >> 6;
    #pragma unroll
    for (int off = 32; off; off >>= 1) {
        s  += __shfl_down(s, off, 64);
        sq += __shfl_down(sq, off, 64);
        mn  = fminf(mn, __shfl_down(mn, off, 64));
        mx  = fmaxf(mx, __shfl_down(mx, off, 64));
    }
    if (lane == 0) red4[wid] = make_float4(s, sq, mn, mx);
    __syncthreads();
    if (threadIdx.x == 0) {
        float4 r = red4[0];
        #pragma unroll
        for (int w = 1; w < 16; ++w) {
            float4 q = red4[w];
            r.x += q.x; r.y += q.y;
            r.z = fminf(r.z, q.z); r.w = fmaxf(r.w, q.w);
        }
        red4[0] = r;
    }
    __syncthreads();
    float4 r = red4[0];
    __syncthreads();
    return r;
}

// K1: per-vector stats + coefficient arrays + histogram (fused). 6 blocks x 1024.
// Block 0 zeroes the counters used by k_main (16 group + marg + final).
__global__ void __launch_bounds__(1024)
k_prep(const float* __restrict__ fused,
       const float* __restrict__ s1,
       const float* __restrict__ s2,
       float2* __restrict__ xa,
       float2* __restrict__ ma,
       float* __restrict__ par,
       float* __restrict__ hcnt,
       float* __restrict__ hmu,
       unsigned int* __restrict__ counters) {
    __shared__ unsigned int cnt[NBIN];
    __shared__ int qs[NBIN];
    int vec = blockIdx.x;
    int b = vec / 3, k = vec % 3;
    const float* src = (k == 0 ? fused : (k == 1 ? s1 : s2)) + b * 16384;
    int tid = threadIdx.x;

    if (vec == 0 && tid < 32) counters[tid] = 0u;   // graph-replay-safe reset
    cnt[tid] = 0u; qs[tid] = 0;

    float v[4];
    float s = 0.f, sq = 0.f, mn = 1e30f, mx = -1e30f;
    #pragma unroll
    for (int t = 0; t < 4; ++t) {
        v[t] = src[tid + t * 1024];
        s += v[t]; sq = fmaf(v[t], v[t], sq);
        mn = fminf(mn, v[t]); mx = fmaxf(mx, v[t]);
    }
    float4 r = block_reduce_stats(s, sq, mn, mx);
    float mean = r.x * (1.0f / 4096.0f);
    float tssq = r.y - 4096.0f * mean * mean;       // Σ(v-mean)^2
    float stdv = sqrtf(fmaxf(tssq, 0.f) / 4095.0f); // ddof=1
    float sigma = fminf(fmaxf(0.2f * stdv, 0.001f), 1.0f);
    float inv = 1.0f / (stdv + 1e-8f);
    float c1 = -0.5f * LOG2E / (sigma * sigma);
    float xmin = (r.z - mean) * inv;
    float xmax = (r.w - mean) * inv;
    float range = fmaxf(xmax - xmin, 1e-6f);
    float inv_bw = (float)NBIN / range;
    float binw = range * (1.0f / NBIN);

    float2* xav = xa + (size_t)vec * N;
    float2* mav = ma + (size_t)vec * N;
    __syncthreads();   // cnt/qs zeroed before atomics
    #pragma unroll
    for (int t = 0; t < 4; ++t) {
        int i = tid + t * 1024;
        float x = (v[t] - mean) * inv;
        float a = c1 * x * x;
        xav[i] = make_float2(x, a);
        mav[i] = make_float2(-2.0f * c1 * x, a);
        float rel = x - xmin;
        int bb = min(NBIN - 1, max(0, (int)(rel * inv_bw)));
        atomicAdd(&cnt[bb], 1u);
        atomicAdd(&qs[bb], (int)rintf(rel * 16384.0f));
    }
    __syncthreads();
    {
        unsigned int c = cnt[tid];
        hcnt[vec * NBIN + tid] = (float)c;
        float mu = c ? xmin + ((float)qs[tid] / (float)c) * (1.0f / 16384.0f)
                     : xmin + (tid + 0.5f) * binw;
        hmu[vec * NBIN + tid] = mu;
    }
    if (tid == 0) {
        par[vec * 8 + 0] = xmin;
        par[vec * 8 + 1] = inv_bw;
        par[vec * 8 + 2] = binw;
        par[vec * 8 + 3] = c1;
    }
}

// K2 (everything else, one kernel): grid = 96 + 4*4*js blocks, 256 threads.
// bid < 96: marginal windowed histogram sweep; bumps marg counter (counters[16]).
// bid >= 96: joint brute force. Per (tt, ib) group of js blocks, the
//   last-finishing block reduces its 1024 i's (deterministic fixed-order),
//   waiting on the marg counter first (all blocks co-resident: 4.4 blk/CU).
//   The 16th group-finisher (counters[17]) computes the final output.
__global__ void __launch_bounds__(256, 8)
k_main(const float2* __restrict__ xa,
       const float2* __restrict__ ma,
       const float* __restrict__ par,
       const float* __restrict__ hcnt,
       const float* __restrict__ hmu,
       float* __restrict__ marg,
       float* __restrict__ msum_part,
       float* __restrict__ part,
       float* __restrict__ A_part,
       float* __restrict__ jsum_part,
       unsigned int* __restrict__ counters,
       float* __restrict__ out, int js) {
    __shared__ float4 sj[128];
    __shared__ float shc[NBIN];
    __shared__ float shm[NBIN];
    __shared__ bool flag;
    __shared__ float svec[6], stask[4], sA[4];
    const int nib = 4;
    int bid = blockIdx.x;
    int tid = threadIdx.x;

    if (bid < 96) {
        int vec = bid >> 4, ic = bid & 15;
        int i = ic * 256 + tid;
        const float* P = par + vec * 8;
        float xmin = P[0], inv_bw = P[1], c1 = P[3];
        const float* hc = hcnt + vec * NBIN;
        const float* hm = hmu + vec * NBIN;
        #pragma unroll
        for (int u = 0; u < 4; ++u) {
            shc[tid + u * 256] = hc[tid + u * 256];
            shm[tid + u * 256] = hm[tid + u * 256];
        }
        __syncthreads();
        float xi = xa[(size_t)vec * N + i].x;
        float R = sqrtf(45.0f / fabsf(c1));      // exp2 cutoff at 2^-45
        int b0 = max(0, (int)((xi - R - xmin) * inv_bw));
        int b1 = min(NBIN - 1, (int)((xi + R - xmin) * inv_bw) + 1);
        float acc = 0.f;
        #pragma unroll 4
        for (int bb = b0; bb <= b1; ++bb) {
            float d = xi - shm[bb];
            acc += shc[bb] * fast_exp2(c1 * d * d);
        }
        float raw = acc * (1.0f / N);
        marg[(size_t)vec * N + i] = raw;
        float tot = block_reduce_sum(raw);   // contains syncthreads: all marg[] stores done
        if (tid == 0) {
            msum_part[bid] = tot;
            __threadfence();
            atomicAdd(&counters[16], 1u);    // marg-done release
        }
        return;
    }

    int bid2 = bid - 96;
    int tt = bid2 / (nib * js);
    int rem = bid2 % (nib * js);
    int ib = rem / js, jsp = rem % js;
    int g = tt * nib + ib;                   // group id 0..15
    int b = tt >> 1, pr = tt & 1;
    int vx = b * 3, vy = b * 3 + 1 + pr;
    int jlen = N / js;
    int j0 = jsp * jlen;
    int ibase = ib * 1024 + tid;

    const float2* xav = xa + (size_t)vx * N;
    const float2* yav = xa + (size_t)vy * N;
    const float2* mxv = ma + (size_t)vx * N;
    const float2* myv = ma + (size_t)vy * N;

    float mx[4], my[4], C[4];
    #pragma unroll
    for (int u = 0; u < 4; ++u) {
        float2 qx = mxv[ibase + u * 256];
        float2 qy = myv[ibase + u * 256];
        mx[u] = qx.x; my[u] = qy.x; C[u] = qx.y + qy.y;
    }
    float acc[4] = {0.f, 0.f, 0.f, 0.f};

    for (int jt = 0; jt < jlen; jt += 128) {
        int cnt = min(128, jlen - jt);
        __syncthreads();
        if (tid < cnt) {
            float2 xq = xav[j0 + jt + tid];
            float2 yq = yav[j0 + jt + tid];
            sj[tid] = make_float4(xq.x, yq.x, xq.y + yq.y, 0.f);
        }
        __syncthreads();
        #pragma unroll 2
        for (int j = 0; j < cnt; j += 2) {
            float4 q0 = sj[j];
            float4 q1 = sj[j + 1];
            float e0[4], e1[4], f0[4], f1[4];
            #pragma unroll
            for (int u = 0; u < 4; ++u) {
                e0[u] = fmaf(my[u], q0.y, fmaf(mx[u], q0.x, C[u])) + q0.z;
                e1[u] = fmaf(my[u], q1.y, fmaf(mx[u], q1.x, C[u])) + q1.z;
            }
            #pragma unroll
            for (int u = 0; u < 4; ++u) {
                f0[u] = fast_exp2(e0[u]);
                f1[u] = fast_exp2(e1[u]);
            }
            #pragma unroll
            for (int u = 0; u < 4; ++u)
                acc[u] += (f0[u] + f1[u]);
        }
    }
    float* dst = part + ((size_t)tt * js + jsp) * N + ibase;
    dst[0]   = acc[0];
    dst[256] = acc[1];
    dst[512] = acc[2];
    dst[768] = acc[3];

    // ---- group completion: last block of this (tt, ib) group reduces ----
    __syncthreads();                         // all dst writes issued
    if (tid == 0) {
        __threadfence();
        unsigned int done = atomicAdd(&counters[g], 1u);
        flag = (done == (unsigned int)(js - 1));
    }
    __syncthreads();
    if (!flag) return;

    // wait for all 96 marg blocks (co-resident grid -> no deadlock)
    if (tid == 0) {
        while (__hip_atomic_load(&counters[16], __ATOMIC_ACQUIRE,
                                 __HIP_MEMORY_SCOPE_AGENT) < 96u) {}
    }
    __syncthreads();
    __threadfence();                         // acquire partials + marg

    float sl = 0.f, al = 0.f;
    #pragma unroll
    for (int u = 0; u < 4; ++u) {
        int i = ibase + u * 256;
        float s = 0.f;
        #pragma unroll 4
        for (int q = 0; q < js; ++q) s += part[((size_t)tt * js + q) * N + i];
        s *= (1.0f / N);
        float rx = marg[(size_t)vx * N + i];
        float ry = marg[(size_t)vy * N + i];
        sl += s;
        al += s * __logf(s / (rx * ry));
    }
    float stot = block_reduce_sum(sl);
    float atot = block_reduce_sum(al);
    if (tid == 0) {
        jsum_part[g] = stot;
        A_part[g] = atot;
        __threadfence();
        unsigned int done2 = atomicAdd(&counters[17], 1u);
        flag = (done2 == 15u);
    }
    __syncthreads();
    if (!flag) return;
    __threadfence();                         // acquire all groups' sums

    // ---- final ----
    if (tid < 6) {
        float ss = 0.f;
        #pragma unroll
        for (int q = 0; q < 16; ++q) ss += msum_part[tid * 16 + q];
        svec[tid] = ss;
    } else if (tid >= 8 && tid < 12) {
        int c = tid - 8;
        float ss = 0.f, aa = 0.f;
        #pragma unroll
        for (int q = 0; q < 4; ++q) {
            ss += jsum_part[c * 4 + q];
            aa += A_part[c * 4 + q];
        }
        stask[c] = ss;
        sA[c] = aa;
    }
    __syncthreads();
    if (tid == 0) {
        float mi = 0.f;
        #pragma unroll
        for (int c = 0; c < 4; ++c) {
            int bb = c >> 1, pp = c & 1;
            int wx = bb * 3, wy = bb * 3 + 1 + pp;
            mi += sA[c] / stask[c] + __logf(svec[wx] * svec[wy] / stask[c]);
        }
        out[0] = -mi * 0.5f;
    }
}

extern "C" void kernel_launch(void* const* d_in, const int* in_sizes, int n_in,
                              void* d_out, int out_size, void* d_ws, size_t ws_size,
                              hipStream_t stream) {
    const float* fused = (const float*)d_in[0];
    const float* s1    = (const float*)d_in[1];
    const float* s2    = (const float*)d_in[2];
    float* out = (float*)d_out;
    float* ws  = (float*)d_ws;

    // ws layout (floats)
    const size_t off_xa   = 0;                          // 6*N*2
    const size_t off_ma   = off_xa + 12 * (size_t)N;    // 6*N*2
    const size_t off_par  = off_ma + 12 * (size_t)N;    // 64
    const size_t off_hc   = off_par + 64;               // 6*NBIN
    const size_t off_hm   = off_hc + 6 * NBIN;          // 6*NBIN
    const size_t off_mg   = off_hm + 6 * NBIN;          // 6*N
    const size_t off_ms   = off_mg + 6 * (size_t)N;     // 96 (+pad)
    const size_t off_A    = off_ms + 128;               // 16
    const size_t off_js   = off_A + 16;                 // 16
    const size_t off_ctr  = off_js + 16;                // 32 uints
    const size_t off_part = off_ctr + 32;               // 4*js*N

    int js = 32;
    while (js > 1 && (off_part + (size_t)4 * js * N) * 4 > ws_size) js >>= 1;

    float2* ws_xa  = (float2*)(ws + off_xa);
    float2* ws_ma  = (float2*)(ws + off_ma);
    float*  ws_par = ws + off_par;
    float*  ws_hc  = ws + off_hc;
    float*  ws_hm  = ws + off_hm;
    float*  ws_mg  = ws + off_mg;
    float*  ws_ms  = ws + off_ms;
    float*  ws_A   = ws + off_A;
    float*  ws_js  = ws + off_js;
    unsigned int* ws_ctr = (unsigned int*)(ws + off_ctr);
    float*  ws_part = ws + off_part;

    k_prep<<<dim3(6), dim3(1024), 0, stream>>>(fused, s1, s2, ws_xa, ws_ma,
                                               ws_par, ws_hc, ws_hm, ws_ctr);
    k_main<<<dim3(96 + 4 * 4 * js), dim3(256), 0, stream>>>(
        ws_xa, ws_ma, ws_par, ws_hc, ws_hm, ws_mg, ws_ms, ws_part,
        ws_A, ws_js, ws_ctr, out, js);
}

// Round 15
// 37.569 us; speedup vs baseline: 1.6530x; 1.6530x over previous
//
#include <hip/hip_runtime.h>

#define N 4096
#define NBIN 1024
#define LOG2E 1.4426950408889634f

__device__ __forceinline__ float fast_exp2(float x) {
#if __has_builtin(__builtin_amdgcn_exp2f)
    return __builtin_amdgcn_exp2f(x);
#else
    return exp2f(x);
#endif
}

__device__ float block_reduce_sum(float v) {
    __shared__ float red[16];
    int lane = threadIdx.x & 63;
    int wid = threadIdx.x >> 6;
    #pragma unroll
    for (int off = 32; off; off >>= 1) v += __shfl_down(v, off, 64);
    if (lane == 0) red[wid] = v;
    __syncthreads();
    if (threadIdx.x == 0) {
        int nw = (int)(blockDim.x >> 6);
        float s = red[0];
        for (int w = 1; w < nw; ++w) s += red[w];
        red[0] = s;
    }
    __syncthreads();
    float r = red[0];
    __syncthreads();
    return r;
}

// Combined (sum, sumsq, min, max) single-pass block reduction, 1024 threads.
__device__ float4 block_reduce_stats(float s, float sq, float mn, float mx) {
    __shared__ float4 red4[16];
    int lane = threadIdx.x & 63;
    int wid = threadIdx.x >> 6;
    #pragma unroll
    for (int off = 32; off; off >>= 1) {
        s  += __shfl_down(s, off, 64);
        sq += __shfl_down(sq, off, 64);
        mn  = fminf(mn, __shfl_down(mn, off, 64));
        mx  = fmaxf(mx, __shfl_down(mx, off, 64));
    }
    if (lane == 0) red4[wid] = make_float4(s, sq, mn, mx);
    __syncthreads();
    if (threadIdx.x == 0) {
        float4 r = red4[0];
        #pragma unroll
        for (int w = 1; w < 16; ++w) {
            float4 q = red4[w];
            r.x += q.x; r.y += q.y;
            r.z = fminf(r.z, q.z); r.w = fmaxf(r.w, q.w);
        }
        red4[0] = r;
    }
    __syncthreads();
    float4 r = red4[0];
    __syncthreads();
    return r;
}

// K1: per-vector stats + coefficient arrays + histogram (fused). 6 blocks x 1024.
// Also zeroes the completion counter used by k_redfin.
__global__ void __launch_bounds__(1024)
k_prep(const float* __restrict__ fused,
       const float* __restrict__ s1,
       const float* __restrict__ s2,
       float2* __restrict__ xa,
       float2* __restrict__ ma,
       float* __restrict__ par,
       float* __restrict__ hcnt,
       float* __restrict__ hmu,
       unsigned int* __restrict__ counter) {
    __shared__ unsigned int cnt[NBIN];
    __shared__ int qs[NBIN];
    int vec = blockIdx.x;
    int b = vec / 3, k = vec % 3;
    const float* src = (k == 0 ? fused : (k == 1 ? s1 : s2)) + b * 16384;
    int tid = threadIdx.x;

    if (vec == 0 && tid == 0) *counter = 0u;   // reset for k_redfin (graph replay safe)
    cnt[tid] = 0u; qs[tid] = 0;

    float v[4];
    float s = 0.f, sq = 0.f, mn = 1e30f, mx = -1e30f;
    #pragma unroll
    for (int t = 0; t < 4; ++t) {
        v[t] = src[tid + t * 1024];
        s += v[t]; sq = fmaf(v[t], v[t], sq);
        mn = fminf(mn, v[t]); mx = fmaxf(mx, v[t]);
    }
    float4 r = block_reduce_stats(s, sq, mn, mx);
    float mean = r.x * (1.0f / 4096.0f);
    float tssq = r.y - 4096.0f * mean * mean;       // Σ(v-mean)^2
    float stdv = sqrtf(fmaxf(tssq, 0.f) / 4095.0f); // ddof=1
    float sigma = fminf(fmaxf(0.2f * stdv, 0.001f), 1.0f);
    float inv = 1.0f / (stdv + 1e-8f);
    float c1 = -0.5f * LOG2E / (sigma * sigma);
    float xmin = (r.z - mean) * inv;
    float xmax = (r.w - mean) * inv;
    float range = fmaxf(xmax - xmin, 1e-6f);
    float inv_bw = (float)NBIN / range;
    float binw = range * (1.0f / NBIN);

    float2* xav = xa + (size_t)vec * N;
    float2* mav = ma + (size_t)vec * N;
    __syncthreads();   // cnt/qs zeroed before atomics
    #pragma unroll
    for (int t = 0; t < 4; ++t) {
        int i = tid + t * 1024;
        float x = (v[t] - mean) * inv;
        float a = c1 * x * x;
        xav[i] = make_float2(x, a);
        mav[i] = make_float2(-2.0f * c1 * x, a);
        float rel = x - xmin;
        int bb = min(NBIN - 1, max(0, (int)(rel * inv_bw)));
        atomicAdd(&cnt[bb], 1u);
        atomicAdd(&qs[bb], (int)rintf(rel * 16384.0f));
    }
    __syncthreads();
    {
        unsigned int c = cnt[tid];
        hcnt[vec * NBIN + tid] = (float)c;
        float mu = c ? xmin + ((float)qs[tid] / (float)c) * (1.0f / 16384.0f)
                     : xmin + (tid + 0.5f) * binw;
        hmu[vec * NBIN + tid] = mu;
    }
    if (tid == 0) {
        par[vec * 8 + 0] = xmin;
        par[vec * 8 + 1] = inv_bw;
        par[vec * 8 + 2] = binw;
        par[vec * 8 + 3] = c1;
    }
}

// K2 (fused marg + joint): grid = 96 + 4*2*js blocks, 256 threads.
// bid < 96: marginal windowed histogram sweep with LDS-staged histogram.
// bid >= 96: joint brute force, IB=8 i's/thread (block covers 2048 i's, nib=2),
//            LDS-staged j-tile, j-range split js ways.
__global__ void __launch_bounds__(256, 8)
k_main(const float2* __restrict__ xa,
       const float2* __restrict__ ma,
       const float* __restrict__ par,
       const float* __restrict__ hcnt,
       const float* __restrict__ hmu,
       float* __restrict__ marg,
       float* __restrict__ msum_part,
       float* __restrict__ part, int js) {
    __shared__ float4 sj[128];
    __shared__ float shc[NBIN];
    __shared__ float shm[NBIN];
    const int nib = 2;
    int bid = blockIdx.x;
    int tid = threadIdx.x;

    if (bid < 96) {
        int vec = bid >> 4, ic = bid & 15;
        int i = ic * 256 + tid;
        const float* P = par + vec * 8;
        float xmin = P[0], inv_bw = P[1], c1 = P[3];
        const float* hc = hcnt + vec * NBIN;
        const float* hm = hmu + vec * NBIN;
        #pragma unroll
        for (int u = 0; u < 4; ++u) {
            shc[tid + u * 256] = hc[tid + u * 256];
            shm[tid + u * 256] = hm[tid + u * 256];
        }
        __syncthreads();
        float xi = xa[(size_t)vec * N + i].x;
        float R = sqrtf(45.0f / fabsf(c1));      // exp2 cutoff at 2^-45
        int b0 = max(0, (int)((xi - R - xmin) * inv_bw));
        int b1 = min(NBIN - 1, (int)((xi + R - xmin) * inv_bw) + 1);
        float acc = 0.f;
        #pragma unroll 4
        for (int bb = b0; bb <= b1; ++bb) {
            float d = xi - shm[bb];
            acc += shc[bb] * fast_exp2(c1 * d * d);
        }
        float raw = acc * (1.0f / N);
        marg[(size_t)vec * N + i] = raw;
        float tot = block_reduce_sum(raw);
        if (tid == 0) msum_part[bid] = tot;
        return;
    }

    int bid2 = bid - 96;
    int tt = bid2 / (nib * js);
    int rem = bid2 % (nib * js);
    int ib = rem / js, jsp = rem % js;
    int b = tt >> 1, pr = tt & 1;
    int vx = b * 3, vy = b * 3 + 1 + pr;
    int jlen = N / js;
    int j0 = jsp * jlen;
    int ibase = ib * 2048 + tid;

    const float2* xav = xa + (size_t)vx * N;
    const float2* yav = xa + (size_t)vy * N;
    const float2* mxv = ma + (size_t)vx * N;
    const float2* myv = ma + (size_t)vy * N;

    float mx[8], my[8], C[8];
    #pragma unroll
    for (int u = 0; u < 8; ++u) {
        float2 qx = mxv[ibase + u * 256];
        float2 qy = myv[ibase + u * 256];
        mx[u] = qx.x; my[u] = qy.x; C[u] = qx.y + qy.y;
    }
    float acc[8] = {0.f, 0.f, 0.f, 0.f, 0.f, 0.f, 0.f, 0.f};

    for (int jt = 0; jt < jlen; jt += 128) {
        int cnt = min(128, jlen - jt);
        __syncthreads();
        if (tid < cnt) {
            float2 xq = xav[j0 + jt + tid];
            float2 yq = yav[j0 + jt + tid];
            sj[tid] = make_float4(xq.x, yq.x, xq.y + yq.y, 0.f);
        }
        __syncthreads();
        #pragma unroll 4
        for (int j = 0; j < cnt; ++j) {
            float4 q0 = sj[j];
            float e[8], f[8];
            #pragma unroll
            for (int u = 0; u < 8; ++u)
                e[u] = fmaf(my[u], q0.y, fmaf(mx[u], q0.x, C[u])) + q0.z;
            #pragma unroll
            for (int u = 0; u < 8; ++u)
                f[u] = fast_exp2(e[u]);
            #pragma unroll
            for (int u = 0; u < 8; ++u)
                acc[u] += f[u];
        }
    }
    float* dst = part + ((size_t)tt * js + jsp) * N + ibase;
    #pragma unroll
    for (int u = 0; u < 8; ++u)
        dst[u * 256] = acc[u];
}

// K3 (fused reduce + final): 64 blocks x 256. Per block: rawj for one
// (task, i-chunk), A = Σ rawj*log(rawj/(rawx*rawy)) and Sj partials.
// Last-finishing block (atomic counter) computes the final output.
__global__ void k_redfin(const float* __restrict__ part,
                         const float* __restrict__ marg,
                         const float* __restrict__ msum_part,
                         float* __restrict__ A_part,
                         float* __restrict__ jsum_part,
                         unsigned int* __restrict__ counter,
                         float* __restrict__ out, int js) {
    __shared__ bool isLast;
    __shared__ float svec[6], stask[4], sA[4];
    int blk = blockIdx.x;
    int tt = blk >> 4;
    int ic = blk & 15;
    int b = tt >> 1, pr = tt & 1;
    int vx = b * 3, vy = b * 3 + 1 + pr;
    int i = ic * 256 + threadIdx.x;
    float s = 0.f;
    #pragma unroll 4
    for (int q = 0; q < js; ++q) s += part[((size_t)tt * js + q) * N + i];
    s *= (1.0f / N);
    float rx = marg[(size_t)vx * N + i];
    float ry = marg[(size_t)vy * N + i];
    float a = s * __logf(s / (rx * ry));
    float stot = block_reduce_sum(s);
    float atot = block_reduce_sum(a);
    if (threadIdx.x == 0) {
        jsum_part[blk] = stot;
        A_part[blk] = atot;
        __threadfence();
        unsigned int done = atomicAdd(counter, 1u);
        isLast = (done == 63u);
    }
    __syncthreads();
    if (!isLast) return;
    __threadfence();   // acquire: see all blocks' partials

    int tid = threadIdx.x;
    if (tid < 6) {
        float ss = 0.f;
        #pragma unroll
        for (int q = 0; q < 16; ++q) ss += msum_part[tid * 16 + q];
        svec[tid] = ss;
    } else if (tid >= 8 && tid < 12) {
        int c = tid - 8;
        float ss = 0.f, aa = 0.f;
        #pragma unroll
        for (int q = 0; q < 16; ++q) {
            ss += jsum_part[c * 16 + q];
            aa += A_part[c * 16 + q];
        }
        stask[c] = ss;
        sA[c] = aa;
    }
    __syncthreads();
    if (tid == 0) {
        float mi = 0.f;
        #pragma unroll
        for (int c = 0; c < 4; ++c) {
            int bb = c >> 1, pp = c & 1;
            int wx = bb * 3, wy = bb * 3 + 1 + pp;
            mi += sA[c] / stask[c] + __logf(svec[wx] * svec[wy] / stask[c]);
        }
        out[0] = -mi * 0.5f;
    }
}

extern "C" void kernel_launch(void* const* d_in, const int* in_sizes, int n_in,
                              void* d_out, int out_size, void* d_ws, size_t ws_size,
                              hipStream_t stream) {
    const float* fused = (const float*)d_in[0];
    const float* s1    = (const float*)d_in[1];
    const float* s2    = (const float*)d_in[2];
    float* out = (float*)d_out;
    float* ws  = (float*)d_ws;

    // ws layout (floats)
    const size_t off_xa   = 0;                          // 6*N*2
    const size_t off_ma   = off_xa + 12 * (size_t)N;    // 6*N*2
    const size_t off_par  = off_ma + 12 * (size_t)N;    // 64
    const size_t off_hc   = off_par + 64;               // 6*NBIN
    const size_t off_hm   = off_hc + 6 * NBIN;          // 6*NBIN
    const size_t off_mg   = off_hm + 6 * NBIN;          // 6*N
    const size_t off_ms   = off_mg + 6 * (size_t)N;     // 96 (+pad)
    const size_t off_A    = off_ms + 128;               // 64
    const size_t off_js   = off_A + 64;                 // 64
    const size_t off_ctr  = off_js + 64;                // 1 (+pad)
    const size_t off_part = off_ctr + 16;               // 4*js*N

    int js = 32;
    while (js > 1 && (off_part + (size_t)4 * js * N) * 4 > ws_size) js >>= 1;

    float2* ws_xa  = (float2*)(ws + off_xa);
    float2* ws_ma  = (float2*)(ws + off_ma);
    float*  ws_par = ws + off_par;
    float*  ws_hc  = ws + off_hc;
    float*  ws_hm  = ws + off_hm;
    float*  ws_mg  = ws + off_mg;
    float*  ws_ms  = ws + off_ms;
    float*  ws_A   = ws + off_A;
    float*  ws_js  = ws + off_js;
    unsigned int* ws_ctr = (unsigned int*)(ws + off_ctr);
    float*  ws_part = ws + off_part;

    k_prep<<<dim3(6), dim3(1024), 0, stream>>>(fused, s1, s2, ws_xa, ws_ma,
                                               ws_par, ws_hc, ws_hm, ws_ctr);
    k_main<<<dim3(96 + 4 * 2 * js), dim3(256), 0, stream>>>(
        ws_xa, ws_ma, ws_par, ws_hc, ws_hm, ws_mg, ws_ms, ws_part, js);
    k_redfin<<<dim3(64), dim3(256), 0, stream>>>(ws_part, ws_mg, ws_ms,
                                                 ws_A, ws_js, ws_ctr, out, js);
}

// Round 16
// 32.989 us; speedup vs baseline: 1.8825x; 1.1388x over previous
//
#include <hip/hip_runtime.h>

#define N 4096
#define NBIN 1024
#define LOG2E 1.4426950408889634f

__device__ __forceinline__ float fast_exp2(float x) {
#if __has_builtin(__builtin_amdgcn_exp2f)
    return __builtin_amdgcn_exp2f(x);
#else
    return exp2f(x);
#endif
}

__device__ float block_reduce_sum(float v) {
    __shared__ float red[16];
    int lane = threadIdx.x & 63;
    int wid = threadIdx.x >> 6;
    #pragma unroll
    for (int off = 32; off; off >>= 1) v += __shfl_down(v, off, 64);
    if (lane == 0) red[wid] = v;
    __syncthreads();
    if (threadIdx.x == 0) {
        int nw = (int)(blockDim.x >> 6);
        float s = red[0];
        for (int w = 1; w < nw; ++w) s += red[w];
        red[0] = s;
    }
    __syncthreads();
    float r = red[0];
    __syncthreads();
    return r;
}

// Combined (sum, sumsq, min, max) single-pass block reduction, 1024 threads.
__device__ float4 block_reduce_stats(float s, float sq, float mn, float mx) {
    __shared__ float4 red4[16];
    int lane = threadIdx.x & 63;
    int wid = threadIdx.x >> 6;
    #pragma unroll
    for (int off = 32; off; off >>= 1) {
        s  += __shfl_down(s, off, 64);
        sq += __shfl_down(sq, off, 64);
        mn  = fminf(mn, __shfl_down(mn, off, 64));
        mx  = fmaxf(mx, __shfl_down(mx, off, 64));
    }
    if (lane == 0) red4[wid] = make_float4(s, sq, mn, mx);
    __syncthreads();
    if (threadIdx.x == 0) {
        float4 r = red4[0];
        #pragma unroll
        for (int w = 1; w < 16; ++w) {
            float4 q = red4[w];
            r.x += q.x; r.y += q.y;
            r.z = fminf(r.z, q.z); r.w = fmaxf(r.w, q.w);
        }
        red4[0] = r;
    }
    __syncthreads();
    float4 r = red4[0];
    __syncthreads();
    return r;
}

// K1: per-vector stats + coefficient arrays + histogram (fused). 6 blocks x 1024.
// xa[vec][j] = (x_j, a_j)   (a = c1*x^2, c1 in log2 units)
// ma[vec][i] = (m_i, a_i)   (m = -2*c1*x)
// par[vec*8 + {0:xmin, 1:inv_binw, 2:binw, 3:c1}]
__global__ void __launch_bounds__(1024)
k_prep(const float* __restrict__ fused,
       const float* __restrict__ s1,
       const float* __restrict__ s2,
       float2* __restrict__ xa,
       float2* __restrict__ ma,
       float* __restrict__ par,
       float* __restrict__ hcnt,
       float* __restrict__ hmu) {
    __shared__ unsigned int cnt[NBIN];
    __shared__ int qs[NBIN];
    int vec = blockIdx.x;
    int b = vec / 3, k = vec % 3;
    const float* src = (k == 0 ? fused : (k == 1 ? s1 : s2)) + b * 16384;
    int tid = threadIdx.x;

    cnt[tid] = 0u; qs[tid] = 0;

    float v[4];
    float s = 0.f, sq = 0.f, mn = 1e30f, mx = -1e30f;
    #pragma unroll
    for (int t = 0; t < 4; ++t) {
        v[t] = src[tid + t * 1024];
        s += v[t]; sq = fmaf(v[t], v[t], sq);
        mn = fminf(mn, v[t]); mx = fmaxf(mx, v[t]);
    }
    float4 r = block_reduce_stats(s, sq, mn, mx);
    float mean = r.x * (1.0f / 4096.0f);
    float tssq = r.y - 4096.0f * mean * mean;       // Σ(v-mean)^2
    float stdv = sqrtf(fmaxf(tssq, 0.f) / 4095.0f); // ddof=1
    float sigma = fminf(fmaxf(0.2f * stdv, 0.001f), 1.0f);
    float inv = 1.0f / (stdv + 1e-8f);
    float c1 = -0.5f * LOG2E / (sigma * sigma);
    float xmin = (r.z - mean) * inv;
    float xmax = (r.w - mean) * inv;
    float range = fmaxf(xmax - xmin, 1e-6f);
    float inv_bw = (float)NBIN / range;
    float binw = range * (1.0f / NBIN);

    float2* xav = xa + (size_t)vec * N;
    float2* mav = ma + (size_t)vec * N;
    __syncthreads();   // cnt/qs zeroed before atomics (also covers reduce reuse)
    #pragma unroll
    for (int t = 0; t < 4; ++t) {
        int i = tid + t * 1024;
        float x = (v[t] - mean) * inv;
        float a = c1 * x * x;
        xav[i] = make_float2(x, a);
        mav[i] = make_float2(-2.0f * c1 * x, a);
        float rel = x - xmin;
        int bb = min(NBIN - 1, max(0, (int)(rel * inv_bw)));
        atomicAdd(&cnt[bb], 1u);
        atomicAdd(&qs[bb], (int)rintf(rel * 16384.0f));
    }
    __syncthreads();
    {
        unsigned int c = cnt[tid];
        hcnt[vec * NBIN + tid] = (float)c;
        float mu = c ? xmin + ((float)qs[tid] / (float)c) * (1.0f / 16384.0f)
                     : xmin + (tid + 0.5f) * binw;
        hmu[vec * NBIN + tid] = mu;
    }
    if (tid == 0) {
        par[vec * 8 + 0] = xmin;
        par[vec * 8 + 1] = inv_bw;
        par[vec * 8 + 2] = binw;
        par[vec * 8 + 3] = c1;
    }
}

// K2 (fused marg + joint): grid = 96 + 4*4*js blocks, 256 threads.
// bid < 96: marginal windowed histogram sweep (vec = bid>>4, chunk = bid&15).
// bid >= 96: joint brute force, tasks tt=0..3 (b=tt>>1, pr=tt&1 -> vx=b*3, vy=b*3+1+pr),
//            IB=4 i's/thread, LDS-staged j-tile, j-range split js ways.
__global__ void __launch_bounds__(256, 8)
k_main(const float2* __restrict__ xa,
       const float2* __restrict__ ma,
       const float* __restrict__ par,
       const float* __restrict__ hcnt,
       const float* __restrict__ hmu,
       float* __restrict__ marg,
       float* __restrict__ msum_part,
       float* __restrict__ part, int js) {
    __shared__ float4 sj[128];
    const int nib = 4;
    int bid = blockIdx.x;
    int tid = threadIdx.x;

    if (bid < 96) {
        int vec = bid >> 4, ic = bid & 15;
        int i = ic * 256 + tid;
        const float* P = par + vec * 8;
        float xmin = P[0], inv_bw = P[1], c1 = P[3];
        float xi = xa[(size_t)vec * N + i].x;
        float R = sqrtf(45.0f / fabsf(c1));      // exp2 cutoff at 2^-45
        int b0 = max(0, (int)((xi - R - xmin) * inv_bw));
        int b1 = min(NBIN - 1, (int)((xi + R - xmin) * inv_bw) + 1);
        const float* hc = hcnt + vec * NBIN;
        const float* hm = hmu + vec * NBIN;
        float acc = 0.f;
        #pragma unroll 4
        for (int bb = b0; bb <= b1; ++bb) {
            float d = xi - hm[bb];
            acc += hc[bb] * fast_exp2(c1 * d * d);
        }
        float raw = acc * (1.0f / N);
        marg[(size_t)vec * N + i] = raw;
        float tot = block_reduce_sum(raw);
        if (tid == 0) msum_part[bid] = tot;
        return;
    }

    int bid2 = bid - 96;
    int tt = bid2 / (nib * js);
    int rem = bid2 % (nib * js);
    int ib = rem / js, jsp = rem % js;
    int b = tt >> 1, pr = tt & 1;
    int vx = b * 3, vy = b * 3 + 1 + pr;
    int jlen = N / js;
    int j0 = jsp * jlen;
    int ibase = ib * 1024 + tid;

    const float2* xav = xa + (size_t)vx * N;
    const float2* yav = xa + (size_t)vy * N;
    const float2* mxv = ma + (size_t)vx * N;
    const float2* myv = ma + (size_t)vy * N;

    float mx[4], my[4], C[4];
    #pragma unroll
    for (int u = 0; u < 4; ++u) {
        float2 qx = mxv[ibase + u * 256];
        float2 qy = myv[ibase + u * 256];
        mx[u] = qx.x; my[u] = qy.x; C[u] = qx.y + qy.y;
    }
    float acc[4] = {0.f, 0.f, 0.f, 0.f};

    for (int jt = 0; jt < jlen; jt += 128) {
        int cnt = min(128, jlen - jt);
        __syncthreads();
        if (tid < cnt) {
            float2 xq = xav[j0 + jt + tid];
            float2 yq = yav[j0 + jt + tid];
            sj[tid] = make_float4(xq.x, yq.x, xq.y + yq.y, 0.f);
        }
        __syncthreads();
        #pragma unroll 2
        for (int j = 0; j < cnt; j += 2) {
            float4 q0 = sj[j];
            float4 q1 = sj[j + 1];
            float e0[4], e1[4], f0[4], f1[4];
            #pragma unroll
            for (int u = 0; u < 4; ++u) {
                e0[u] = fmaf(my[u], q0.y, fmaf(mx[u], q0.x, C[u])) + q0.z;
                e1[u] = fmaf(my[u], q1.y, fmaf(mx[u], q1.x, C[u])) + q1.z;
            }
            #pragma unroll
            for (int u = 0; u < 4; ++u) {
                f0[u] = fast_exp2(e0[u]);
                f1[u] = fast_exp2(e1[u]);
            }
            #pragma unroll
            for (int u = 0; u < 4; ++u)
                acc[u] += (f0[u] + f1[u]);
        }
    }
    float* dst = part + ((size_t)tt * js + jsp) * N + ibase;
    dst[0]   = acc[0];
    dst[256] = acc[1];
    dst[512] = acc[2];
    dst[768] = acc[3];
}

// K3: reduce joint j-split partials -> rawj, then per-chunk MI numerator
// A = Σ rawj*log(rawj/(rawx*rawy)) and Sj partials. 64 blocks x 256.
__global__ void k_reduce(const float* __restrict__ part,
                         const float* __restrict__ marg,
                         float* __restrict__ A_part,
                         float* __restrict__ jsum_part, int js) {
    int blk = blockIdx.x;
    int tt = blk >> 4;
    int ic = blk & 15;
    int b = tt >> 1, pr = tt & 1;
    int vx = b * 3, vy = b * 3 + 1 + pr;
    int i = ic * 256 + threadIdx.x;
    float s = 0.f;
    #pragma unroll 4
    for (int q = 0; q < js; ++q) s += part[((size_t)tt * js + q) * N + i];
    s *= (1.0f / N);
    float rx = marg[(size_t)vx * N + i];
    float ry = marg[(size_t)vy * N + i];
    float a = s * __logf(s / (rx * ry));
    // two block reductions (sequential, reuses the same LDS safely)
    float stot = block_reduce_sum(s);
    float atot = block_reduce_sum(a);
    if (threadIdx.x == 0) {
        jsum_part[blk] = stot;
        A_part[blk] = atot;
    }
}

// K4: final. 1 block x 128 threads.
// MI_c = A_c/Sj_c + log(Sx*Sy/Sj_c); out = -(ΣMI)/2.
__global__ void k_fin(const float* __restrict__ A_part,
                      const float* __restrict__ jsum_part,
                      const float* __restrict__ msum_part,
                      float* __restrict__ out) {
    __shared__ float svec[6], stask[4], sA[4];
    int tid = threadIdx.x;
    if (tid < 6) {
        float s = 0.f;
        #pragma unroll
        for (int q = 0; q < 16; ++q) s += msum_part[tid * 16 + q];
        svec[tid] = s;
    } else if (tid >= 8 && tid < 12) {
        int c = tid - 8;
        float s = 0.f, a = 0.f;
        #pragma unroll
        for (int q = 0; q < 16; ++q) {
            s += jsum_part[c * 16 + q];
            a += A_part[c * 16 + q];
        }
        stask[c] = s;
        sA[c] = a;
    }
    __syncthreads();
    if (tid == 0) {
        float mi = 0.f;
        #pragma unroll
        for (int c = 0; c < 4; ++c) {
            int b = c >> 1, pr = c & 1;
            int vx = b * 3, vy = b * 3 + 1 + pr;
            mi += sA[c] / stask[c] + __logf(svec[vx] * svec[vy] / stask[c]);
        }
        out[0] = -mi * 0.5f;
    }
}

extern "C" void kernel_launch(void* const* d_in, const int* in_sizes, int n_in,
                              void* d_out, int out_size, void* d_ws, size_t ws_size,
                              hipStream_t stream) {
    const float* fused = (const float*)d_in[0];
    const float* s1    = (const float*)d_in[1];
    const float* s2    = (const float*)d_in[2];
    float* out = (float*)d_out;
    float* ws  = (float*)d_ws;

    // ws layout (floats)
    const size_t off_xa   = 0;                          // 6*N*2
    const size_t off_ma   = off_xa + 12 * (size_t)N;    // 6*N*2
    const size_t off_par  = off_ma + 12 * (size_t)N;    // 64
    const size_t off_hc   = off_par + 64;               // 6*NBIN
    const size_t off_hm   = off_hc + 6 * NBIN;          // 6*NBIN
    const size_t off_mg   = off_hm + 6 * NBIN;          // 6*N
    const size_t off_ms   = off_mg + 6 * (size_t)N;     // 96 (+pad)
    const size_t off_A    = off_ms + 128;               // 64
    const size_t off_js   = off_A + 64;                 // 64
    const size_t off_part = off_js + 64;                // 4*js*N

    int js = 32;
    while (js > 1 && (off_part + (size_t)4 * js * N) * 4 > ws_size) js >>= 1;

    float* ws_xa_f = ws + off_xa;
    float2* ws_xa  = (float2*)ws_xa_f;
    float2* ws_ma  = (float2*)(ws + off_ma);
    float*  ws_par = ws + off_par;
    float*  ws_hc  = ws + off_hc;
    float*  ws_hm  = ws + off_hm;
    float*  ws_mg  = ws + off_mg;
    float*  ws_ms  = ws + off_ms;
    float*  ws_A   = ws + off_A;
    float*  ws_js  = ws + off_js;
    float*  ws_part = ws + off_part;

    k_prep<<<dim3(6), dim3(1024), 0, stream>>>(fused, s1, s2, ws_xa, ws_ma,
                                               ws_par, ws_hc, ws_hm);
    k_main<<<dim3(96 + 4 * 4 * js), dim3(256), 0, stream>>>(
        ws_xa, ws_ma, ws_par, ws_hc, ws_hm, ws_mg, ws_ms, ws_part, js);
    k_reduce<<<dim3(64), dim3(256), 0, stream>>>(ws_part, ws_mg, ws_A, ws_js, js);
    k_fin<<<dim3(1), dim3(128), 0, stream>>>(ws_A, ws_js, ws_ms, out);
}